// Round 6
// baseline (232.344 us; speedup 1.0000x reference)
//
#include <hip/hip_runtime.h>
#include <math.h>

// Problem constants (match reference: D=256, HID=512, N=100000)
#define DDIM   256
#define HID    512
#define SBLK   512   // number of stm partial blocks (also ltm)

// Workspace layout (float offsets)
#define OFF_M     0
#define OFF_L     (SBLK)
#define OFF_SACC  (2*SBLK)
#define OFF_LACC  (OFF_SACC + SBLK*DDIM)
#define OFF_FUSED (OFF_LACC + SBLK*DDIM)
#define OFF_H     (OFF_FUSED + 3*DDIM)
// total floats = 2*512 + 2*512*256 + 768 + 512 = 264448  (~1.01 MB)

typedef float v4f __attribute__((ext_vector_type(4)));

// Non-temporal 16B load: global_load_dwordx4 ... nt — read-once stream, no
// L2/L3 pollution; still hits resident lines. (R5: this + real register room
// broke the 80us plateau; keep both.)
__device__ __forceinline__ v4f nt_load4(const v4f* p) {
    return __builtin_nontemporal_load(p);
}

// ---------------------------------------------------------------------------
// Kernel A: blocks [0,512): stm online-softmax partials; [512,1024): ltm sums.
// 256 threads = 4 waves; 1024 blocks -> 4 blocks/CU, 16 waves/CU, VGPR cap
// 128 (launch_bounds(256,4)) so the depth-1 OCT prefetch lives in registers.
// R6 change: work quantum 4 rows -> 8 rows (8 KB) per iteration per wave:
// one shuffle-reduce phase (8 interleaved chains) + ONE rescale per 8 rows,
// double the bytes in flight per wave.
// ---------------------------------------------------------------------------
__global__ __launch_bounds__(256, 4) void kA(const float* __restrict__ x_t,
                                             const float* __restrict__ stm_emb,
                                             const float* __restrict__ stm_w,
                                             const float* __restrict__ ltm_emb,
                                             const float* __restrict__ ltm_w,
                                             float* __restrict__ ws, int N)
{
    const int t    = threadIdx.x;
    const int lane = t & 63;
    const int wave = t >> 6;          // 4 waves

    __shared__ float s_acc[4][DDIM];  // 4 KB merge scratch
    __shared__ float s_m[4];
    __shared__ float s_l[4];

    const v4f x4 = reinterpret_cast<const v4f*>(x_t)[lane];
    const int NO  = N >> 3;           // full row-octs (12500 for N=100000)
    const int bid = blockIdx.x;

    if (bid < SBLK) {
        // ---- STM: fused online-softmax + weighted accumulate ----
        const int b  = bid;
        const int os = (int)(((long long)b     * NO) / SBLK);
        const int oe = (int)(((long long)(b+1) * NO) / SBLK);
        const v4f* emb4 = reinterpret_cast<const v4f*>(stm_emb);
        const v4f* w4   = reinterpret_cast<const v4f*>(stm_w);

        float m = -1e30f, l = 0.f;
        float ax = 0.f, ay = 0.f, az = 0.f, aw = 0.f;

        int o = os + wave;
        if (o < oe) {
            size_t base = (size_t)o * 512 + lane;       // v4f index of row 8o
            v4f E[8], W0, W1;
            #pragma unroll
            for (int j = 0; j < 8; ++j) E[j] = nt_load4(emb4 + base + j * 64);
            W0 = nt_load4(w4 + 2 * o);
            W1 = nt_load4(w4 + 2 * o + 1);
            while (true) {
                const int  on   = o + 4;
                const bool more = on < oe;
                const int  op   = more ? on : o;        // clamp: cache-hit reload
                size_t pb = (size_t)op * 512 + lane;
                v4f F[8], Wn0, Wn1;
                #pragma unroll
                for (int j = 0; j < 8; ++j) F[j] = nt_load4(emb4 + pb + j * 64);
                Wn0 = nt_load4(w4 + 2 * op);
                Wn1 = nt_load4(w4 + 2 * op + 1);

                float p[8];
                #pragma unroll
                for (int j = 0; j < 8; ++j)
                    p[j] = E[j].x*x4.x + E[j].y*x4.y + E[j].z*x4.z + E[j].w*x4.w;
                #pragma unroll
                for (int off = 32; off > 0; off >>= 1) { // 8 independent chains
                    #pragma unroll
                    for (int j = 0; j < 8; ++j)
                        p[j] += __shfl_xor(p[j], off, 64);
                }
                const float wv[8] = {W0.x, W0.y, W0.z, W0.w, W1.x, W1.y, W1.z, W1.w};
                float s[8];
                #pragma unroll
                for (int j = 0; j < 8; ++j) s[j] = p[j] * wv[j];

                float smax = s[0];
                #pragma unroll
                for (int j = 1; j < 8; ++j) smax = fmaxf(smax, s[j]);
                float mn = fmaxf(m, smax);
                float sc = __expf(m - mn);
                float q[8];
                #pragma unroll
                for (int j = 0; j < 8; ++j) q[j] = __expf(s[j] - mn);
                m = mn;
                float ql = 0.f, qx = 0.f, qy = 0.f, qz = 0.f, qw = 0.f;
                #pragma unroll
                for (int j = 0; j < 8; ++j) {
                    ql += q[j];
                    qx += q[j] * E[j].x; qy += q[j] * E[j].y;
                    qz += q[j] * E[j].z; qw += q[j] * E[j].w;
                }
                l  = l*sc  + ql;
                ax = ax*sc + qx; ay = ay*sc + qy;
                az = az*sc + qz; aw = aw*sc + qw;

                if (!more) break;
                #pragma unroll
                for (int j = 0; j < 8; ++j) E[j] = F[j];
                W0 = Wn0; W1 = Wn1; o = on;
            }
        }
        // tail rows (N & 7, zero for N=100000) handled by last stm block
        if (b == SBLK - 1) {
            const int tail = N & 7;
            for (int idx = wave; idx < tail; idx += 4) {
                const int r = (NO << 3) + idx;
                v4f e = reinterpret_cast<const v4f*>(stm_emb)[(size_t)r * 64 + lane];
                float wvv = stm_w[r];
                float pp = e.x*x4.x + e.y*x4.y + e.z*x4.z + e.w*x4.w;
                #pragma unroll
                for (int off = 32; off > 0; off >>= 1)
                    pp += __shfl_xor(pp, off, 64);
                float ss = pp * wvv;
                float mn = fmaxf(m, ss);
                float sc = __expf(m - mn);
                float qq = __expf(ss - mn);
                m = mn;
                l  = l*sc + qq;
                ax = ax*sc + qq*e.x; ay = ay*sc + qq*e.y;
                az = az*sc + qq*e.z; aw = aw*sc + qq*e.w;
            }
        }

        s_acc[wave][lane*4+0] = ax;
        s_acc[wave][lane*4+1] = ay;
        s_acc[wave][lane*4+2] = az;
        s_acc[wave][lane*4+3] = aw;
        if (lane == 0) { s_m[wave] = m; s_l[wave] = l; }
        __syncthreads();

        float M  = fmaxf(fmaxf(s_m[0], s_m[1]), fmaxf(s_m[2], s_m[3]));
        float e0 = __expf(s_m[0] - M), e1 = __expf(s_m[1] - M);
        float e2 = __expf(s_m[2] - M), e3 = __expf(s_m[3] - M);
        float L  = s_l[0]*e0 + s_l[1]*e1 + s_l[2]*e2 + s_l[3]*e3;
        float av = s_acc[0][t]*e0 + s_acc[1][t]*e1 + s_acc[2][t]*e2 + s_acc[3][t]*e3;
        ws[OFF_SACC + b*DDIM + t] = av;
        if (t == 0) { ws[OFF_M + b] = M; ws[OFF_L + b] = L; }
    } else {
        // ---- LTM: plain weighted sum, same pipelined NT oct stream ----
        const int b  = bid - SBLK;
        const int os = (int)(((long long)b     * NO) / SBLK);
        const int oe = (int)(((long long)(b+1) * NO) / SBLK);
        const v4f* emb4 = reinterpret_cast<const v4f*>(ltm_emb);
        const v4f* w4   = reinterpret_cast<const v4f*>(ltm_w);

        float ax = 0.f, ay = 0.f, az = 0.f, aw = 0.f;
        int o = os + wave;
        if (o < oe) {
            size_t base = (size_t)o * 512 + lane;
            v4f E[8], W0, W1;
            #pragma unroll
            for (int j = 0; j < 8; ++j) E[j] = nt_load4(emb4 + base + j * 64);
            W0 = nt_load4(w4 + 2 * o);
            W1 = nt_load4(w4 + 2 * o + 1);
            while (true) {
                const int  on   = o + 4;
                const bool more = on < oe;
                const int  op   = more ? on : o;
                size_t pb = (size_t)op * 512 + lane;
                v4f F[8], Wn0, Wn1;
                #pragma unroll
                for (int j = 0; j < 8; ++j) F[j] = nt_load4(emb4 + pb + j * 64);
                Wn0 = nt_load4(w4 + 2 * op);
                Wn1 = nt_load4(w4 + 2 * op + 1);

                const float wv[8] = {W0.x, W0.y, W0.z, W0.w, W1.x, W1.y, W1.z, W1.w};
                #pragma unroll
                for (int j = 0; j < 8; ++j) {
                    ax += wv[j] * E[j].x; ay += wv[j] * E[j].y;
                    az += wv[j] * E[j].z; aw += wv[j] * E[j].w;
                }

                if (!more) break;
                #pragma unroll
                for (int j = 0; j < 8; ++j) E[j] = F[j];
                W0 = Wn0; W1 = Wn1; o = on;
            }
        }
        if (b == SBLK - 1) {
            const int tail = N & 7;
            for (int idx = wave; idx < tail; idx += 4) {
                const int r = (NO << 3) + idx;
                v4f e = reinterpret_cast<const v4f*>(ltm_emb)[(size_t)r * 64 + lane];
                float wvv = ltm_w[r];
                ax += wvv*e.x; ay += wvv*e.y; az += wvv*e.z; aw += wvv*e.w;
            }
        }

        s_acc[wave][lane*4+0] = ax;
        s_acc[wave][lane*4+1] = ay;
        s_acc[wave][lane*4+2] = az;
        s_acc[wave][lane*4+3] = aw;
        __syncthreads();
        float av = s_acc[0][t] + s_acc[1][t] + s_acc[2][t] + s_acc[3][t];
        ws[OFF_LACC + b*DDIM + t] = av;
    }
}

// ---------------------------------------------------------------------------
// Kernel B: merge the 512 softmax partials + 512 ltm partials -> fused[768].
// grid=8 blocks; each block redundantly computes global (M,L) and an LDS
// table of per-block scales sc[b]=exp(m_b-M), then owns 32 d-columns.
// Block 0 also copies x_t into fused, inits h=b1 and out=b2.
// ---------------------------------------------------------------------------
__global__ __launch_bounds__(256) void kB(const float* __restrict__ x_t,
                                          const float* __restrict__ b1,
                                          const float* __restrict__ b2,
                                          float* __restrict__ ws,
                                          float* __restrict__ out)
{
    __shared__ float red[256];
    __shared__ float scl[SBLK];
    __shared__ float r1[256];
    __shared__ float r2[256];
    const int t = threadIdx.x;

    const float* ws_m = ws + OFF_M;
    const float* ws_l = ws + OFF_L;
    const float* sacc = ws + OFF_SACC;
    const float* lacc = ws + OFF_LACC;
    float* fused = ws + OFF_FUSED;
    float* hbuf  = ws + OFF_H;

    // global max M over 512 block maxima
    float m0 = ws_m[t], m1 = ws_m[t + 256];
    red[t] = fmaxf(m0, m1); __syncthreads();
    for (int s = 128; s > 0; s >>= 1) {
        if (t < s) red[t] = fmaxf(red[t], red[t + s]);
        __syncthreads();
    }
    const float M = red[0];
    __syncthreads();

    // per-partial scales into LDS, then global denominator L
    float sc0 = __expf(m0 - M), sc1 = __expf(m1 - M);
    scl[t] = sc0; scl[t + 256] = sc1;
    red[t] = ws_l[t] * sc0 + ws_l[t + 256] * sc1;
    __syncthreads();
    for (int s = 128; s > 0; s >>= 1) {
        if (t < s) red[t] += red[t + s];
        __syncthreads();
    }
    const float L = red[0];
    __syncthreads();

    // this block owns d in [d0, d0+32)
    const int ell = t & 31;
    const int g   = t >> 5;          // 8 groups of 32 lanes
    const int d0  = blockIdx.x * 32;

    float sa = 0.f, la = 0.f;
    #pragma unroll 4
    for (int b = g; b < SBLK; b += 8) {
        sa += sacc[b*DDIM + d0 + ell] * scl[b];
        la += lacc[b*DDIM + d0 + ell];
    }
    r1[t] = sa; r2[t] = la;
    __syncthreads();
    if (g == 0) {
        float S = 0.f, Qs = 0.f;
        #pragma unroll
        for (int gg = 0; gg < 8; gg++) { S += r1[gg*32 + ell]; Qs += r2[gg*32 + ell]; }
        fused[DDIM   + d0 + ell] = S / L;   // r_s
        fused[2*DDIM + d0 + ell] = Qs;      // r_l
    }

    if (blockIdx.x == 0) {
        fused[t] = x_t[t];                  // x part of fused
        hbuf[t]        = b1[t];             // init h with bias (atomics add later)
        hbuf[t + 256]  = b1[t + 256];
        out[t]         = b2[t];             // init out with bias
    }
}

// ---------------------------------------------------------------------------
// Kernel C: h += fused @ w1 over a k-chunk of 64. grid = 12 kchunks x 2 halves.
// ---------------------------------------------------------------------------
__global__ __launch_bounds__(256) void kC(const float* __restrict__ w1,
                                          float* __restrict__ ws)
{
    __shared__ float fl[64];
    const int t     = threadIdx.x;
    const int k0    = (blockIdx.x >> 1) * 64;
    const int h_idx = (blockIdx.x & 1) * 256 + t;
    const float* fused = ws + OFF_FUSED;
    float* hbuf = ws + OFF_H;

    if (t < 64) fl[t] = fused[k0 + t];
    __syncthreads();

    float acc = 0.f;
    #pragma unroll 16
    for (int k = 0; k < 64; k++)
        acc += fl[k] * w1[(k0 + k) * HID + h_idx];   // coalesced over h_idx
    atomicAdd(&hbuf[h_idx], acc);
}

// ---------------------------------------------------------------------------
// Kernel D: out += relu(h) @ w2 over a k-chunk of 64. grid = 8 kchunks.
// ---------------------------------------------------------------------------
__global__ __launch_bounds__(256) void kD(const float* __restrict__ w2,
                                          const float* __restrict__ ws,
                                          float* __restrict__ out)
{
    __shared__ float hl[64];
    const int t  = threadIdx.x;
    const int k0 = blockIdx.x * 64;
    const float* hbuf = ws + OFF_H;

    if (t < 64) hl[t] = fmaxf(hbuf[k0 + t], 0.f);
    __syncthreads();

    float acc = 0.f;
    #pragma unroll 16
    for (int k = 0; k < 64; k++)
        acc += hl[k] * w2[(k0 + k) * DDIM + t];      // coalesced over t
    atomicAdd(&out[t], acc);
}

extern "C" void kernel_launch(void* const* d_in, const int* in_sizes, int n_in,
                              void* d_out, int out_size, void* d_ws, size_t ws_size,
                              hipStream_t stream)
{
    const float* x_t     = (const float*)d_in[0];
    const float* stm_emb = (const float*)d_in[1];
    const float* stm_w   = (const float*)d_in[2];
    const float* ltm_emb = (const float*)d_in[3];
    const float* ltm_w   = (const float*)d_in[4];
    const float* w1      = (const float*)d_in[5];
    const float* b1      = (const float*)d_in[6];
    const float* w2      = (const float*)d_in[7];
    const float* b2      = (const float*)d_in[8];
    float* out = (float*)d_out;
    float* ws  = (float*)d_ws;
    const int N = in_sizes[2];   // 100000

    kA<<<2 * SBLK, 256, 0, stream>>>(x_t, stm_emb, stm_w, ltm_emb, ltm_w, ws, N);
    kB<<<8,        256, 0, stream>>>(x_t, b1, b2, ws, out);
    kC<<<24,       256, 0, stream>>>(w1, ws);
    kD<<<8,        256, 0, stream>>>(w2, ws, out);
}

// Round 7
// 230.709 us; speedup vs baseline: 1.0071x; 1.0071x over previous
//
#include <hip/hip_runtime.h>
#include <math.h>

// Problem constants (match reference: D=256, HID=512, N=100000)
#define DDIM   256
#define HID    512
#define SBLK   512   // number of stm partial blocks (also ltm)

// Workspace layout (float offsets)
#define OFF_M     0
#define OFF_L     (SBLK)
#define OFF_SACC  (2*SBLK)
#define OFF_LACC  (OFF_SACC + SBLK*DDIM)
#define OFF_FUSED (OFF_LACC + SBLK*DDIM)
#define OFF_H     (OFF_FUSED + 3*DDIM)
// total floats = 2*512 + 2*512*256 + 768 + 512 = 264448  (~1.01 MB)

typedef float v4f __attribute__((ext_vector_type(4)));

// Non-temporal 16B load: global_load_dwordx4 ... nt — read-once stream, no
// L2/L3 pollution; still hits resident lines. (R5: this + real register room
// broke the 80us plateau; keep both.)
__device__ __forceinline__ v4f nt_load4(const v4f* p) {
    return __builtin_nontemporal_load(p);
}

// ---------------------------------------------------------------------------
// Kernel A: blocks [0,512): stm online-softmax partials; [512,1024): ltm sums.
// 256 threads = 4 waves; 1024 blocks -> 4 blocks/CU, 16 waves/CU, VGPR cap
// 128 (launch_bounds(256,4)). 8-row (8 KB) quantum per wave per step.
// R7: ping-pong double buffer (A/B octs alternate) — removes the E=F rotate
// (32 v_movs + vmcnt(0) drain per iter) and removes the clamped last-iter
// prefetch, which with NT (no-allocate) loads was re-fetching 8 KB/wave from
// HBM = 32 MB (~15%) over-read. Prefetch branch is wave-uniform.
// ---------------------------------------------------------------------------
__global__ __launch_bounds__(256, 4) void kA(const float* __restrict__ x_t,
                                             const float* __restrict__ stm_emb,
                                             const float* __restrict__ stm_w,
                                             const float* __restrict__ ltm_emb,
                                             const float* __restrict__ ltm_w,
                                             float* __restrict__ ws, int N)
{
    const int t    = threadIdx.x;
    const int lane = t & 63;
    const int wave = t >> 6;          // 4 waves

    __shared__ float s_acc[4][DDIM];  // 4 KB merge scratch
    __shared__ float s_m[4];
    __shared__ float s_l[4];

    const v4f x4 = reinterpret_cast<const v4f*>(x_t)[lane];
    const int NO  = N >> 3;           // full row-octs (12500 for N=100000)
    const int bid = blockIdx.x;

    if (bid < SBLK) {
        // ---- STM: fused online-softmax + weighted accumulate ----
        const int b  = bid;
        const int os = (int)(((long long)b     * NO) / SBLK);
        const int oe = (int)(((long long)(b+1) * NO) / SBLK);
        const v4f* emb4 = reinterpret_cast<const v4f*>(stm_emb);
        const v4f* w4   = reinterpret_cast<const v4f*>(stm_w);

        float m = -1e30f, l = 0.f;
        float ax = 0.f, ay = 0.f, az = 0.f, aw = 0.f;

        v4f A[8], Aw0, Aw1;
        v4f B[8], Bw0, Bw1;

        // process one oct held in registers (E[8] + weight pair)
        auto proc = [&](const v4f* E, const v4f& Wa, const v4f& Wb) {
            float p[8];
            #pragma unroll
            for (int j = 0; j < 8; ++j)
                p[j] = E[j].x*x4.x + E[j].y*x4.y + E[j].z*x4.z + E[j].w*x4.w;
            #pragma unroll
            for (int off = 32; off > 0; off >>= 1) {   // 8 interleaved chains
                #pragma unroll
                for (int j = 0; j < 8; ++j)
                    p[j] += __shfl_xor(p[j], off, 64);
            }
            const float wv[8] = {Wa.x, Wa.y, Wa.z, Wa.w, Wb.x, Wb.y, Wb.z, Wb.w};
            float s[8];
            #pragma unroll
            for (int j = 0; j < 8; ++j) s[j] = p[j] * wv[j];
            float smax = s[0];
            #pragma unroll
            for (int j = 1; j < 8; ++j) smax = fmaxf(smax, s[j]);
            float mn = fmaxf(m, smax);
            float sc = __expf(m - mn);
            float q[8];
            #pragma unroll
            for (int j = 0; j < 8; ++j) q[j] = __expf(s[j] - mn);
            m = mn;
            float ql = 0.f, qx = 0.f, qy = 0.f, qz = 0.f, qw = 0.f;
            #pragma unroll
            for (int j = 0; j < 8; ++j) {
                ql += q[j];
                qx += q[j] * E[j].x; qy += q[j] * E[j].y;
                qz += q[j] * E[j].z; qw += q[j] * E[j].w;
            }
            l  = l*sc  + ql;
            ax = ax*sc + qx; ay = ay*sc + qy;
            az = az*sc + qz; aw = aw*sc + qw;
        };

        int o = os + wave;             // per-wave uniform
        if (o < oe) {
            {
                size_t ba = (size_t)o * 512 + lane;
                #pragma unroll
                for (int j = 0; j < 8; ++j) A[j] = nt_load4(emb4 + ba + j * 64);
                Aw0 = nt_load4(w4 + 2 * o);
                Aw1 = nt_load4(w4 + 2 * o + 1);
            }
            while (true) {
                int n1 = o + 4;
                if (n1 < oe) {                     // wave-uniform branch
                    size_t bb = (size_t)n1 * 512 + lane;
                    #pragma unroll
                    for (int j = 0; j < 8; ++j) B[j] = nt_load4(emb4 + bb + j * 64);
                    Bw0 = nt_load4(w4 + 2 * n1);
                    Bw1 = nt_load4(w4 + 2 * n1 + 1);
                }
                proc(A, Aw0, Aw1);                 // oct o
                if (n1 >= oe) break;
                o = n1;

                int n2 = o + 4;
                if (n2 < oe) {
                    size_t ba = (size_t)n2 * 512 + lane;
                    #pragma unroll
                    for (int j = 0; j < 8; ++j) A[j] = nt_load4(emb4 + ba + j * 64);
                    Aw0 = nt_load4(w4 + 2 * n2);
                    Aw1 = nt_load4(w4 + 2 * n2 + 1);
                }
                proc(B, Bw0, Bw1);                 // oct o (== n1)
                if (n2 >= oe) break;
                o = n2;
            }
        }
        // tail rows (N & 7, zero for N=100000) handled by last stm block
        if (b == SBLK - 1) {
            const int tail = N & 7;
            for (int idx = wave; idx < tail; idx += 4) {
                const int r = (NO << 3) + idx;
                v4f e = reinterpret_cast<const v4f*>(stm_emb)[(size_t)r * 64 + lane];
                float wvv = stm_w[r];
                float pp = e.x*x4.x + e.y*x4.y + e.z*x4.z + e.w*x4.w;
                #pragma unroll
                for (int off = 32; off > 0; off >>= 1)
                    pp += __shfl_xor(pp, off, 64);
                float ss = pp * wvv;
                float mn = fmaxf(m, ss);
                float sc = __expf(m - mn);
                float qq = __expf(ss - mn);
                m = mn;
                l  = l*sc + qq;
                ax = ax*sc + qq*e.x; ay = ay*sc + qq*e.y;
                az = az*sc + qq*e.z; aw = aw*sc + qq*e.w;
            }
        }

        s_acc[wave][lane*4+0] = ax;
        s_acc[wave][lane*4+1] = ay;
        s_acc[wave][lane*4+2] = az;
        s_acc[wave][lane*4+3] = aw;
        if (lane == 0) { s_m[wave] = m; s_l[wave] = l; }
        __syncthreads();

        float M  = fmaxf(fmaxf(s_m[0], s_m[1]), fmaxf(s_m[2], s_m[3]));
        float e0 = __expf(s_m[0] - M), e1 = __expf(s_m[1] - M);
        float e2 = __expf(s_m[2] - M), e3 = __expf(s_m[3] - M);
        float L  = s_l[0]*e0 + s_l[1]*e1 + s_l[2]*e2 + s_l[3]*e3;
        float av = s_acc[0][t]*e0 + s_acc[1][t]*e1 + s_acc[2][t]*e2 + s_acc[3][t]*e3;
        ws[OFF_SACC + b*DDIM + t] = av;
        if (t == 0) { ws[OFF_M + b] = M; ws[OFF_L + b] = L; }
    } else {
        // ---- LTM: plain weighted sum, same ping-pong NT oct stream ----
        const int b  = bid - SBLK;
        const int os = (int)(((long long)b     * NO) / SBLK);
        const int oe = (int)(((long long)(b+1) * NO) / SBLK);
        const v4f* emb4 = reinterpret_cast<const v4f*>(ltm_emb);
        const v4f* w4   = reinterpret_cast<const v4f*>(ltm_w);

        float ax = 0.f, ay = 0.f, az = 0.f, aw = 0.f;

        v4f A[8], Aw0, Aw1;
        v4f B[8], Bw0, Bw1;

        auto proc = [&](const v4f* E, const v4f& Wa, const v4f& Wb) {
            const float wv[8] = {Wa.x, Wa.y, Wa.z, Wa.w, Wb.x, Wb.y, Wb.z, Wb.w};
            #pragma unroll
            for (int j = 0; j < 8; ++j) {
                ax += wv[j] * E[j].x; ay += wv[j] * E[j].y;
                az += wv[j] * E[j].z; aw += wv[j] * E[j].w;
            }
        };

        int o = os + wave;
        if (o < oe) {
            {
                size_t ba = (size_t)o * 512 + lane;
                #pragma unroll
                for (int j = 0; j < 8; ++j) A[j] = nt_load4(emb4 + ba + j * 64);
                Aw0 = nt_load4(w4 + 2 * o);
                Aw1 = nt_load4(w4 + 2 * o + 1);
            }
            while (true) {
                int n1 = o + 4;
                if (n1 < oe) {
                    size_t bb = (size_t)n1 * 512 + lane;
                    #pragma unroll
                    for (int j = 0; j < 8; ++j) B[j] = nt_load4(emb4 + bb + j * 64);
                    Bw0 = nt_load4(w4 + 2 * n1);
                    Bw1 = nt_load4(w4 + 2 * n1 + 1);
                }
                proc(A, Aw0, Aw1);
                if (n1 >= oe) break;
                o = n1;

                int n2 = o + 4;
                if (n2 < oe) {
                    size_t ba = (size_t)n2 * 512 + lane;
                    #pragma unroll
                    for (int j = 0; j < 8; ++j) A[j] = nt_load4(emb4 + ba + j * 64);
                    Aw0 = nt_load4(w4 + 2 * n2);
                    Aw1 = nt_load4(w4 + 2 * n2 + 1);
                }
                proc(B, Bw0, Bw1);
                if (n2 >= oe) break;
                o = n2;
            }
        }
        if (b == SBLK - 1) {
            const int tail = N & 7;
            for (int idx = wave; idx < tail; idx += 4) {
                const int r = (NO << 3) + idx;
                v4f e = reinterpret_cast<const v4f*>(ltm_emb)[(size_t)r * 64 + lane];
                float wvv = ltm_w[r];
                ax += wvv*e.x; ay += wvv*e.y; az += wvv*e.z; aw += wvv*e.w;
            }
        }

        s_acc[wave][lane*4+0] = ax;
        s_acc[wave][lane*4+1] = ay;
        s_acc[wave][lane*4+2] = az;
        s_acc[wave][lane*4+3] = aw;
        __syncthreads();
        float av = s_acc[0][t] + s_acc[1][t] + s_acc[2][t] + s_acc[3][t];
        ws[OFF_LACC + b*DDIM + t] = av;
    }
}

// ---------------------------------------------------------------------------
// Kernel B: merge the 512 softmax partials + 512 ltm partials -> fused[768].
// grid=8 blocks; each block redundantly computes global (M,L) and an LDS
// table of per-block scales sc[b]=exp(m_b-M), then owns 32 d-columns.
// Block 0 also copies x_t into fused, inits h=b1 and out=b2.
// ---------------------------------------------------------------------------
__global__ __launch_bounds__(256) void kB(const float* __restrict__ x_t,
                                          const float* __restrict__ b1,
                                          const float* __restrict__ b2,
                                          float* __restrict__ ws,
                                          float* __restrict__ out)
{
    __shared__ float red[256];
    __shared__ float scl[SBLK];
    __shared__ float r1[256];
    __shared__ float r2[256];
    const int t = threadIdx.x;

    const float* ws_m = ws + OFF_M;
    const float* ws_l = ws + OFF_L;
    const float* sacc = ws + OFF_SACC;
    const float* lacc = ws + OFF_LACC;
    float* fused = ws + OFF_FUSED;
    float* hbuf  = ws + OFF_H;

    // global max M over 512 block maxima
    float m0 = ws_m[t], m1 = ws_m[t + 256];
    red[t] = fmaxf(m0, m1); __syncthreads();
    for (int s = 128; s > 0; s >>= 1) {
        if (t < s) red[t] = fmaxf(red[t], red[t + s]);
        __syncthreads();
    }
    const float M = red[0];
    __syncthreads();

    // per-partial scales into LDS, then global denominator L
    float sc0 = __expf(m0 - M), sc1 = __expf(m1 - M);
    scl[t] = sc0; scl[t + 256] = sc1;
    red[t] = ws_l[t] * sc0 + ws_l[t + 256] * sc1;
    __syncthreads();
    for (int s = 128; s > 0; s >>= 1) {
        if (t < s) red[t] += red[t + s];
        __syncthreads();
    }
    const float L = red[0];
    __syncthreads();

    // this block owns d in [d0, d0+32)
    const int ell = t & 31;
    const int g   = t >> 5;          // 8 groups of 32 lanes
    const int d0  = blockIdx.x * 32;

    float sa = 0.f, la = 0.f;
    #pragma unroll 4
    for (int b = g; b < SBLK; b += 8) {
        sa += sacc[b*DDIM + d0 + ell] * scl[b];
        la += lacc[b*DDIM + d0 + ell];
    }
    r1[t] = sa; r2[t] = la;
    __syncthreads();
    if (g == 0) {
        float S = 0.f, Qs = 0.f;
        #pragma unroll
        for (int gg = 0; gg < 8; gg++) { S += r1[gg*32 + ell]; Qs += r2[gg*32 + ell]; }
        fused[DDIM   + d0 + ell] = S / L;   // r_s
        fused[2*DDIM + d0 + ell] = Qs;      // r_l
    }

    if (blockIdx.x == 0) {
        fused[t] = x_t[t];                  // x part of fused
        hbuf[t]        = b1[t];             // init h with bias (atomics add later)
        hbuf[t + 256]  = b1[t + 256];
        out[t]         = b2[t];             // init out with bias
    }
}

// ---------------------------------------------------------------------------
// Kernel C: h += fused @ w1 over a k-chunk of 64. grid = 12 kchunks x 2 halves.
// ---------------------------------------------------------------------------
__global__ __launch_bounds__(256) void kC(const float* __restrict__ w1,
                                          float* __restrict__ ws)
{
    __shared__ float fl[64];
    const int t     = threadIdx.x;
    const int k0    = (blockIdx.x >> 1) * 64;
    const int h_idx = (blockIdx.x & 1) * 256 + t;
    const float* fused = ws + OFF_FUSED;
    float* hbuf = ws + OFF_H;

    if (t < 64) fl[t] = fused[k0 + t];
    __syncthreads();

    float acc = 0.f;
    #pragma unroll 16
    for (int k = 0; k < 64; k++)
        acc += fl[k] * w1[(k0 + k) * HID + h_idx];   // coalesced over h_idx
    atomicAdd(&hbuf[h_idx], acc);
}

// ---------------------------------------------------------------------------
// Kernel D: out += relu(h) @ w2 over a k-chunk of 64. grid = 8 kchunks.
// ---------------------------------------------------------------------------
__global__ __launch_bounds__(256) void kD(const float* __restrict__ w2,
                                          const float* __restrict__ ws,
                                          float* __restrict__ out)
{
    __shared__ float hl[64];
    const int t  = threadIdx.x;
    const int k0 = blockIdx.x * 64;
    const float* hbuf = ws + OFF_H;

    if (t < 64) hl[t] = fmaxf(hbuf[k0 + t], 0.f);
    __syncthreads();

    float acc = 0.f;
    #pragma unroll 16
    for (int k = 0; k < 64; k++)
        acc += hl[k] * w2[(k0 + k) * DDIM + t];      // coalesced over t
    atomicAdd(&out[t], acc);
}

extern "C" void kernel_launch(void* const* d_in, const int* in_sizes, int n_in,
                              void* d_out, int out_size, void* d_ws, size_t ws_size,
                              hipStream_t stream)
{
    const float* x_t     = (const float*)d_in[0];
    const float* stm_emb = (const float*)d_in[1];
    const float* stm_w   = (const float*)d_in[2];
    const float* ltm_emb = (const float*)d_in[3];
    const float* ltm_w   = (const float*)d_in[4];
    const float* w1      = (const float*)d_in[5];
    const float* b1      = (const float*)d_in[6];
    const float* w2      = (const float*)d_in[7];
    const float* b2      = (const float*)d_in[8];
    float* out = (float*)d_out;
    float* ws  = (float*)d_ws;
    const int N = in_sizes[2];   // 100000

    kA<<<2 * SBLK, 256, 0, stream>>>(x_t, stm_emb, stm_w, ltm_emb, ltm_w, ws, N);
    kB<<<8,        256, 0, stream>>>(x_t, b1, b2, ws, out);
    kC<<<24,       256, 0, stream>>>(w1, ws);
    kD<<<8,        256, 0, stream>>>(w2, ws, out);
}